// Round 6
// baseline (389.300 us; speedup 1.0000x reference)
//
#include <hip/hip_runtime.h>

#define EDIM 300
#define NB   128
#define NQ   16
#define ND   1024
#define NK   11
#define BLOCK 128
#define MDOC  2
#define DOCS_PER_BLOCK 128              // 64 lanes * MDOC; both waves cover same docs
#define BLOCKS_PER_B   8                // 1024 / 128
#define Q4STRIDE 75                     // float4 per q row
#define PW 132                          // padded doc width (breaks pow2)

// ---------------- Kernel 0: normalize query embeddings into ws ----------------
// grid = B*Q blocks of 64 (one wave per query row)
__global__ void qnorm_kernel(const int* __restrict__ qtoks,
                             const float* __restrict__ emb,
                             float* __restrict__ qn) {
    int row  = blockIdx.x;          // b*16 + q
    int lane = threadIdx.x;         // 0..63
    int tok  = qtoks[row];
    const float* src = emb + (size_t)tok * EDIM;
    float v[5];
    float ssq = 0.f;
#pragma unroll
    for (int j = 0; j < 5; ++j) {
        int e = lane + 64 * j;
        v[j] = (e < EDIM) ? src[e] : 0.f;
        ssq += v[j] * v[j];
    }
#pragma unroll
    for (int off = 32; off >= 1; off >>= 1)
        ssq += __shfl_xor(ssq, off, 64);
    float rn = 1.0f / (sqrtf(ssq) + 1e-9f);
#pragma unroll
    for (int j = 0; j < 5; ++j) {
        int e = lane + 64 * j;
        if (e < EDIM) qn[(size_t)row * EDIM + e] = v[j] * rn;
    }
}

// ---------------- Kernel 1: sim + RBF partial sums ----------------
// grid = 1024 blocks x 128 thr (4 blocks/CU -> 8 waves/CU, 2/SIMD).
// Block = (b, 128 docs). Wave w (=tid>>6) owns E-half w (38/37 float4 chunks,
// 600B sequential streams — R4's proven access pattern). Lane owns 2 whole-
// half doc rows. q-vectors read straight from global qn with WAVE-UNIFORM
// addresses (L1-resident 19.2KB/b tile, broadcast; no LDS in the hot loop).
__global__ __launch_bounds__(BLOCK) void knrm_main(
    const int*   __restrict__ dtoks,
    const float* __restrict__ emb,
    const float* __restrict__ qn,
    const float* __restrict__ mus,
    const float* __restrict__ sigmas,
    float*       __restrict__ part) {
    __shared__ __align__(16) float psim[NQ * PW];   // 8.4 KB
    __shared__ float pssq[PW];
    __shared__ float red_s[NK * NQ * 8];            // 5.6 KB

    const int blk   = blockIdx.x;
    const int b     = blk >> 3;
    const int dbase = (blk & 7) * DOCS_PER_BLOCK;
    const int tid   = threadIdx.x;
    const int lane  = tid & 63;
    const int w     = tid >> 6;                     // e-half, wave-uniform
    const int c0    = w ? 38 : 0;
    const int nch   = w ? 37 : 38;

    const int d0 = dbase + lane * MDOC;
    int2 tks = *(const int2*)&dtoks[b * ND + d0];
    const float4* dp0 = (const float4*)(emb + (size_t)tks.x * EDIM) + c0;
    const float4* dp1 = (const float4*)(emb + (size_t)tks.y * EDIM) + c0;
    const float4* qp  = (const float4*)(qn) + (size_t)b * NQ * Q4STRIDE + c0;

    float sims[MDOC][NQ];
#pragma unroll
    for (int m = 0; m < MDOC; ++m)
#pragma unroll
        for (int q = 0; q < NQ; ++q) sims[m][q] = 0.f;
    float ssq0 = 0.f, ssq1 = 0.f;

    float4 a0 = dp0[0], a1 = dp1[0];
    for (int c = 0; c < nch; ++c) {
        int cn = (c + 1 < nch) ? c + 1 : c;         // clamp: stay in-row
        float4 n0 = dp0[cn], n1 = dp1[cn];
        ssq0 += a0.x*a0.x + a0.y*a0.y + a0.z*a0.z + a0.w*a0.w;
        ssq1 += a1.x*a1.x + a1.y*a1.y + a1.z*a1.z + a1.w*a1.w;
#pragma unroll
        for (int q = 0; q < NQ; ++q) {
            float4 qv = qp[q * Q4STRIDE + c];       // wave-uniform addr
            sims[0][q] += qv.x*a0.x + qv.y*a0.y + qv.z*a0.z + qv.w*a0.w;
            sims[1][q] += qv.x*a1.x + qv.y*a1.y + qv.z*a1.z + qv.w*a1.w;
        }
        a0 = n0; a1 = n1;
    }

    // ---- combine the two E-half waves through LDS ----
    if (w == 0) {
#pragma unroll
        for (int q = 0; q < NQ; ++q) {
            psim[q * PW + lane * 2]     = sims[0][q];
            psim[q * PW + lane * 2 + 1] = sims[1][q];
        }
        pssq[lane * 2]     = ssq0;
        pssq[lane * 2 + 1] = ssq1;
    }
    __syncthreads();
    if (w == 1) {
#pragma unroll
        for (int q = 0; q < NQ; ++q) {
            psim[q * PW + lane * 2]     += sims[0][q];
            psim[q * PW + lane * 2 + 1] += sims[1][q];
        }
        pssq[lane * 2]     += ssq0;
        pssq[lane * 2 + 1] += ssq1;
    }
    __syncthreads();
    {   // normalize: thread = doc. pad docs (tok 0): ssq=0 -> sim stays 0.
        float rn = 1.0f / (sqrtf(pssq[tid]) + 1e-9f);
#pragma unroll
        for (int q = 0; q < NQ; ++q) psim[q * PW + tid] *= rn;
    }
    __syncthreads();

    // ---- RBF bank: thread = (q, doc-slice s of 8), 16 docs each ----
    {
        const int q = tid & 15;
        const int s = tid >> 4;
        float mu[NK], cc[NK], acc[NK];
#pragma unroll
        for (int k = 0; k < NK; ++k) {
            mu[k] = mus[k];
            float sg = sigmas[k];
            cc[k] = -0.5f / (sg * sg);
            acc[k] = 0.f;
        }
        const float* row = psim + q * PW + s * 16;
#pragma unroll
        for (int i = 0; i < 4; ++i) {
            float4 s4 = *(const float4*)(row + i * 4);
#pragma unroll
            for (int k = 0; k < NK; ++k) {
                float e0 = s4.x - mu[k], e1 = s4.y - mu[k];
                float e2 = s4.z - mu[k], e3 = s4.w - mu[k];
                acc[k] += __expf(cc[k]*e0*e0) + __expf(cc[k]*e1*e1)
                        + __expf(cc[k]*e2*e2) + __expf(cc[k]*e3*e3);
            }
        }
#pragma unroll
        for (int k = 0; k < NK; ++k) red_s[(k * NQ + q) * 8 + s] = acc[k];
    }
    __syncthreads();

    // NK*NQ = 176 > BLOCK = 128: stride the write (R3 bug class).
    for (int t = tid; t < NK * NQ; t += BLOCK) {
        float r = 0.f;
#pragma unroll
        for (int j = 0; j < 8; ++j) r += red_s[t * 8 + j];
        part[blk * (NK * NQ) + t] = r;
    }
}

// ---------------- Kernel 2: sum partials, masked log-sum over q, FC ----------------
__global__ void knrm_final(const float* __restrict__ part,
                           const int*   __restrict__ qtoks,
                           const float* __restrict__ fc_w,
                           const float* __restrict__ fc_b,
                           float*       __restrict__ out) {
    __shared__ float red[NK * NQ];
    __shared__ float ks[NK];
    int b = blockIdx.x;
    int t = threadIdx.x;
    if (t < NK * NQ) {
        int q = t & 15;
        float r = 0.f;
        for (int j = 0; j < BLOCKS_PER_B; ++j)
            r += part[(b * BLOCKS_PER_B + j) * (NK * NQ) + t];
        red[t] = (qtoks[b * NQ + q] != 0) ? logf(r + 1e-6f) : 0.f;
    }
    __syncthreads();
    if (t < NK) {
        float s = 0.f;
        for (int q = 0; q < NQ; ++q) s += red[t * NQ + q];
        ks[t] = s * fc_w[t];
    }
    __syncthreads();
    if (t == 0) {
        float s = fc_b[0];
        for (int k = 0; k < NK; ++k) s += ks[k];
        out[b] = s;
    }
}

extern "C" void kernel_launch(void* const* d_in, const int* in_sizes, int n_in,
                              void* d_out, int out_size, void* d_ws, size_t ws_size,
                              hipStream_t stream) {
    const int*   doctoks   = (const int*)  d_in[0];   // [128,1024]
    const int*   querytoks = (const int*)  d_in[1];   // [128,16]
    // d_in[2] = query_idf: unused by the reference
    const float* emb       = (const float*)d_in[3];   // [100000,300]
    const float* mus       = (const float*)d_in[4];   // [11]
    const float* sigmas    = (const float*)d_in[5];   // [11]
    const float* fc_w      = (const float*)d_in[6];   // [1,11]
    const float* fc_b      = (const float*)d_in[7];   // [1]
    float* out = (float*)d_out;                        // [128]

    float* qn   = (float*)d_ws;                        // 2048*300 floats = 2.46 MB
    float* part = qn + (size_t)NB * NQ * EDIM;         // [1024][176] floats

    qnorm_kernel<<<NB * NQ, 64, 0, stream>>>(querytoks, emb, qn);
    knrm_main<<<NB * BLOCKS_PER_B, BLOCK, 0, stream>>>(doctoks, emb, qn,
                                                       mus, sigmas, part);
    knrm_final<<<NB, 192, 0, stream>>>(part, querytoks, fc_w, fc_b, out);
}

// Round 7
// 253.251 us; speedup vs baseline: 1.5372x; 1.5372x over previous
//
#include <hip/hip_runtime.h>

#define EDIM 300
#define NB   128
#define NQ   16
#define ND   1024
#define NK   11
#define BLOCK 128
#define MDOC  4
#define DOCS_PER_BLOCK (BLOCK * MDOC)   // 512
#define BLOCKS_PER_B   2                // 1024 / 512
#define NCHUNK 75                       // EDIM/4
#define SIMW (DOCS_PER_BLOCK + 4)       // 516 floats: breaks pow2 stride, 16B align

// ---------------- Kernel 1: fused qnorm + sim + RBF partial sums ----------------
// grid = 256 blocks x 128 threads. Block = (b, 512 docs). R4 dataflow (proven
// 81MB FETCH): thread owns M=4 WHOLE doc rows streamed float4-sequentially;
// q-vectors broadcast from LDS. R7 change: depth-2 software pipeline — chunk
// c+2's four row-loads are issued before chunk c's FMAs, putting ~1100 cyc of
// compute between load issue and use to cover ~900 cyc HBM latency (R4 was
// depth-1 = 544 cyc and stalled ~1300 cyc/iter; occupancy is capped at 2
// waves/CU by total thread count, so latency must be hidden with ILP).
__global__ __launch_bounds__(BLOCK) void knrm_main(
    const int*   __restrict__ dtoks,
    const int*   __restrict__ qtoks,
    const float* __restrict__ emb,
    const float* __restrict__ mus,
    const float* __restrict__ sigmas,
    float*       __restrict__ part) {
    __shared__ __align__(16) float qn_s[NQ * EDIM];    // 19.2 KB
    __shared__ __align__(16) float sim_t[NQ * SIMW];   // 33.0 KB
    __shared__ float rs_s[NQ];
    __shared__ float red_s[NK * NQ * 8];               // 5.6 KB

    const int blk  = blockIdx.x;
    const int b    = blk >> 1;
    const int half = blk & 1;
    const int tid  = threadIdx.x;

    // ---- stage raw q rows (L2/L3-hot gather), normalize in-block ----
    for (int i = tid; i < NQ * EDIM; i += BLOCK) {
        int q = i / EDIM;
        int e = i - q * EDIM;
        qn_s[i] = emb[(size_t)qtoks[b * NQ + q] * EDIM + e];
    }
    __syncthreads();
    {
        int q = tid >> 3, j = tid & 7;
        float ss = 0.f;
        for (int e = j; e < EDIM; e += 8) { float v = qn_s[q * EDIM + e]; ss += v * v; }
        ss += __shfl_xor(ss, 1, 64);
        ss += __shfl_xor(ss, 2, 64);
        ss += __shfl_xor(ss, 4, 64);
        if (j == 0) rs_s[q] = 1.0f / (sqrtf(ss) + 1e-9f);
    }
    __syncthreads();
    for (int i = tid; i < NQ * EDIM; i += BLOCK) qn_s[i] *= rs_s[i / EDIM];
    __syncthreads();

    // ---- main compute: 4 whole doc rows per thread, depth-2 pipeline ----
    const int d0 = half * DOCS_PER_BLOCK + tid * MDOC;
    int4 tks = *(const int4*)&dtoks[b * ND + d0];
    const float4* rp0 = (const float4*)(emb + (size_t)tks.x * EDIM);
    const float4* rp1 = (const float4*)(emb + (size_t)tks.y * EDIM);
    const float4* rp2 = (const float4*)(emb + (size_t)tks.z * EDIM);
    const float4* rp3 = (const float4*)(emb + (size_t)tks.w * EDIM);

    float sims[MDOC][NQ];
#pragma unroll
    for (int m = 0; m < MDOC; ++m)
#pragma unroll
        for (int q = 0; q < NQ; ++q) sims[m][q] = 0.f;
    float ssq0 = 0.f, ssq1 = 0.f, ssq2 = 0.f, ssq3 = 0.f;

    float4 buf[2][MDOC];

#define LOADC(ST, C)                                                           \
    do {                                                                       \
        buf[ST][0] = rp0[(C)]; buf[ST][1] = rp1[(C)];                          \
        buf[ST][2] = rp2[(C)]; buf[ST][3] = rp3[(C)];                          \
    } while (0)

#define BODYC(ST, C)                                                           \
    do {                                                                       \
        float4 d0v = buf[ST][0], d1v = buf[ST][1];                             \
        float4 d2v = buf[ST][2], d3v = buf[ST][3];                             \
        if ((C) + 2 < NCHUNK) LOADC(ST, (C) + 2);  /* issue 2 iters ahead */   \
        ssq0 += d0v.x*d0v.x + d0v.y*d0v.y + d0v.z*d0v.z + d0v.w*d0v.w;         \
        ssq1 += d1v.x*d1v.x + d1v.y*d1v.y + d1v.z*d1v.z + d1v.w*d1v.w;         \
        ssq2 += d2v.x*d2v.x + d2v.y*d2v.y + d2v.z*d2v.z + d2v.w*d2v.w;         \
        ssq3 += d3v.x*d3v.x + d3v.y*d3v.y + d3v.z*d3v.z + d3v.w*d3v.w;         \
        const float* qb = qn_s + (C) * 4;                                      \
        _Pragma("unroll")                                                      \
        for (int q = 0; q < NQ; ++q) {                                         \
            float4 qv = *(const float4*)(qb + q * EDIM); /* LDS broadcast */   \
            sims[0][q] += qv.x*d0v.x + qv.y*d0v.y + qv.z*d0v.z + qv.w*d0v.w;   \
            sims[1][q] += qv.x*d1v.x + qv.y*d1v.y + qv.z*d1v.z + qv.w*d1v.w;   \
            sims[2][q] += qv.x*d2v.x + qv.y*d2v.y + qv.z*d2v.z + qv.w*d2v.w;   \
            sims[3][q] += qv.x*d3v.x + qv.y*d3v.y + qv.z*d3v.z + qv.w*d3v.w;   \
        }                                                                      \
    } while (0)

    LOADC(0, 0);
    LOADC(1, 1);
    for (int c = 0; c + 1 < NCHUNK; c += 2) {   // c = 0,2,...,72
        BODYC(0, c);
        BODYC(1, c + 1);
    }
    BODYC(0, NCHUNK - 1);                       // chunk 74 (even -> stage 0)
#undef BODYC
#undef LOADC

    // pad docs (tok 0): zero row -> ssq=0 -> sim=0, matches reference masking
    float rn0 = 1.0f / (sqrtf(ssq0) + 1e-9f);
    float rn1 = 1.0f / (sqrtf(ssq1) + 1e-9f);
    float rn2 = 1.0f / (sqrtf(ssq2) + 1e-9f);
    float rn3 = 1.0f / (sqrtf(ssq3) + 1e-9f);

#pragma unroll
    for (int q = 0; q < NQ; ++q) {
        *(float4*)&sim_t[q * SIMW + tid * 4] =
            make_float4(sims[0][q]*rn0, sims[1][q]*rn1, sims[2][q]*rn2, sims[3][q]*rn3);
    }
    __syncthreads();

    // ---- RBF bank: thread = (q, doc-slice s of 8), 64 docs each ----
    {
        const int q = tid & 15;
        const int s = tid >> 4;          // 0..7
        float mu[NK], cc[NK], acc[NK];
#pragma unroll
        for (int k = 0; k < NK; ++k) {
            mu[k] = mus[k];
            float sg = sigmas[k];
            cc[k] = -0.5f / (sg * sg);
            acc[k] = 0.f;
        }
        const float* row = sim_t + q * SIMW + s * 64;
        for (int i = 0; i < 16; ++i) {
            float4 s4 = *(const float4*)(row + i * 4);
#pragma unroll
            for (int k = 0; k < NK; ++k) {
                float e0 = s4.x - mu[k], e1 = s4.y - mu[k];
                float e2 = s4.z - mu[k], e3 = s4.w - mu[k];
                acc[k] += __expf(cc[k]*e0*e0) + __expf(cc[k]*e1*e1)
                        + __expf(cc[k]*e2*e2) + __expf(cc[k]*e3*e3);
            }
        }
#pragma unroll
        for (int k = 0; k < NK; ++k) red_s[(k * NQ + q) * 8 + s] = acc[k];
    }
    __syncthreads();

    // NK*NQ = 176 > BLOCK = 128: stride the write (R3 bug class).
    for (int t = tid; t < NK * NQ; t += BLOCK) {
        float r = 0.f;
#pragma unroll
        for (int j = 0; j < 8; ++j) r += red_s[t * 8 + j];
        part[blk * (NK * NQ) + t] = r;   // non-atomic per-block partial
    }
}

// ---------------- Kernel 2: sum partials, masked log-sum over q, FC ----------------
__global__ void knrm_final(const float* __restrict__ part,
                           const int*   __restrict__ qtoks,
                           const float* __restrict__ fc_w,
                           const float* __restrict__ fc_b,
                           float*       __restrict__ out) {
    __shared__ float red[NK * NQ];
    __shared__ float ks[NK];
    int b = blockIdx.x;
    int t = threadIdx.x;
    if (t < NK * NQ) {
        int q = t & 15;
        float r = 0.f;
        for (int j = 0; j < BLOCKS_PER_B; ++j)
            r += part[(b * BLOCKS_PER_B + j) * (NK * NQ) + t];
        red[t] = (qtoks[b * NQ + q] != 0) ? logf(r + 1e-6f) : 0.f;
    }
    __syncthreads();
    if (t < NK) {
        float s = 0.f;
        for (int q = 0; q < NQ; ++q) s += red[t * NQ + q];
        ks[t] = s * fc_w[t];
    }
    __syncthreads();
    if (t == 0) {
        float s = fc_b[0];
        for (int k = 0; k < NK; ++k) s += ks[k];
        out[b] = s;
    }
}

extern "C" void kernel_launch(void* const* d_in, const int* in_sizes, int n_in,
                              void* d_out, int out_size, void* d_ws, size_t ws_size,
                              hipStream_t stream) {
    const int*   doctoks   = (const int*)  d_in[0];   // [128,1024]
    const int*   querytoks = (const int*)  d_in[1];   // [128,16]
    // d_in[2] = query_idf: unused by the reference
    const float* emb       = (const float*)d_in[3];   // [100000,300]
    const float* mus       = (const float*)d_in[4];   // [11]
    const float* sigmas    = (const float*)d_in[5];   // [11]
    const float* fc_w      = (const float*)d_in[6];   // [1,11]
    const float* fc_b      = (const float*)d_in[7];   // [1]
    float* out = (float*)d_out;                        // [128]

    float* part = (float*)d_ws;                        // [256][176] floats

    knrm_main<<<NB * BLOCKS_PER_B, BLOCK, 0, stream>>>(doctoks, querytoks, emb,
                                                       mus, sigmas, part);
    knrm_final<<<NB, 192, 0, stream>>>(part, querytoks, fc_w, fc_b, out);
}

// Round 8
// 222.395 us; speedup vs baseline: 1.7505x; 1.1387x over previous
//
#include <hip/hip_runtime.h>

#define EDIM 300
#define NB   128
#define NQ   16
#define ND   1024
#define NK   11
#define BLOCK 128
#define MDOC  4
#define TDOCS 256                 // docs per block
#define BLOCKS_PER_B 4            // 1024 / 256
#define NPANEL 10                 // 9 full 32-float panels + one 12-float remainder
#define PPITCH 36                 // panel row pitch in floats (32 + 4 pad; 36%32==4 -> baseline banks)
#define SIMP 260                  // sim_t row pitch (256 + 4 pad)

// ---------------- Kernel 1: fused qnorm + staged sim + RBF partials ----------------
// grid = 512 blocks x 128 thr (2 blocks/CU -> 4 waves/CU, all SIMDs busy).
// Block = (b, 256 docs). R8 change: doc rows are STAGED COALESCED into LDS
// (8 lanes x float4 = 128B contiguous per row-slice) instead of per-lane
// scattered 16B global streams — R1/R4/R7 all plateaued ~100us at the same
// 9.8M scattered-16B-request count; staging cuts requests 8x. Compute: lane
// owns rows {l, l+64, l+128, l+192} (stride-64 so LDS reads keep the
// conflict-free 4l bank pattern); wave w handles q-half w (8 q's), so the
// two waves need no sim reduction. q broadcast from LDS as before.
__global__ __launch_bounds__(BLOCK) void knrm_main(
    const int*   __restrict__ dtoks,
    const int*   __restrict__ qtoks,
    const float* __restrict__ emb,
    const float* __restrict__ mus,
    const float* __restrict__ sigmas,
    float*       __restrict__ part) {
    __shared__ __align__(16) float qn_s[NQ * EDIM];      // 19.2 KB
    __shared__ __align__(16) float panel[TDOCS * PPITCH];// 36.9 KB
    __shared__ int   dtok_s[TDOCS];                      // 1 KB
    __shared__ float rs_s[NQ];
    __shared__ __align__(16) float sim_t[NQ * SIMP];     // 16.6 KB
    __shared__ float red_s[NK * NQ * 8];                 // 5.6 KB
    // total ~77.6 KB -> 2 blocks/CU

    const int blk   = blockIdx.x;
    const int b     = blk >> 2;
    const int dbase = (blk & 3) * TDOCS;
    const int tid   = threadIdx.x;
    const int lane  = tid & 63;
    const int w     = tid >> 6;          // q-half (wave-uniform)

    // ---- doc-token tile + raw q rows (coalesced gathers) ----
    for (int i = tid; i < TDOCS; i += BLOCK) dtok_s[i] = dtoks[b * ND + dbase + i];
    for (int i = tid; i < NQ * EDIM; i += BLOCK) {
        int q = i / EDIM, e = i - q * EDIM;
        qn_s[i] = emb[(size_t)qtoks[b * NQ + q] * EDIM + e];
    }
    __syncthreads();
    {   // q norms
        int q = tid >> 3, j = tid & 7;
        float ss = 0.f;
        for (int e = j; e < EDIM; e += 8) { float v = qn_s[q * EDIM + e]; ss += v * v; }
        ss += __shfl_xor(ss, 1, 64);
        ss += __shfl_xor(ss, 2, 64);
        ss += __shfl_xor(ss, 4, 64);
        if (j == 0) rs_s[q] = 1.0f / (sqrtf(ss) + 1e-9f);
    }
    __syncthreads();
    for (int i = tid; i < NQ * EDIM; i += BLOCK) qn_s[i] *= rs_s[i / EDIM];
    // (visibility of qn_s covered by the sync inside the panel loop)

    float sims[MDOC][8];
#pragma unroll
    for (int m = 0; m < MDOC; ++m)
#pragma unroll
        for (int qq = 0; qq < 8; ++qq) sims[m][qq] = 0.f;
    float ssq[MDOC] = {0.f, 0.f, 0.f, 0.f};

    const int s  = tid & 7;              // 128B slice index within a panel row
    const int r0 = tid >> 3;             // 0..15

    for (int p = 0; p < NPANEL; ++p) {
        __syncthreads();                 // previous panel fully consumed; qn_s/dtok_s visible
        // ---- stage panel p: rows r0+16j, slice s -> lanes 0..7 cover 128B contiguous ----
        if (p < 9 || s < 3) {            // remainder panel has only 12 floats (3 slices)
#pragma unroll
            for (int j = 0; j < 16; ++j) {
                int r = r0 + 16 * j;
                const float* src = emb + (size_t)dtok_s[r] * EDIM + p * 32 + s * 4;
                *(float4*)&panel[r * PPITCH + s * 4] = *(const float4*)src;
            }
        }
        __syncthreads();
        // ---- compute on panel p ----
        const int cmax = (p == 9) ? 3 : 8;
        for (int cc = 0; cc < cmax; ++cc) {
            float4 dv[MDOC];
#pragma unroll
            for (int m = 0; m < MDOC; ++m)
                dv[m] = *(const float4*)&panel[(lane + 64 * m) * PPITCH + cc * 4];
#pragma unroll
            for (int m = 0; m < MDOC; ++m)
                ssq[m] += dv[m].x*dv[m].x + dv[m].y*dv[m].y + dv[m].z*dv[m].z + dv[m].w*dv[m].w;
            const float* qb = qn_s + (size_t)w * 8 * EDIM + (p * 8 + cc) * 4;
#pragma unroll
            for (int qq = 0; qq < 8; ++qq) {
                float4 qv = *(const float4*)(qb + qq * EDIM);   // LDS broadcast
#pragma unroll
                for (int m = 0; m < MDOC; ++m) {
                    sims[m][qq] += qv.x*dv[m].x + qv.y*dv[m].y + qv.z*dv[m].z + qv.w*dv[m].w;
                }
            }
        }
    }

    // ---- normalize + write sim_t (pad docs: tok0 -> zero row -> sim 0) ----
#pragma unroll
    for (int m = 0; m < MDOC; ++m) {
        float rn = 1.0f / (sqrtf(ssq[m]) + 1e-9f);
#pragma unroll
        for (int qq = 0; qq < 8; ++qq)
            sim_t[(w * 8 + qq) * SIMP + lane + 64 * m] = sims[m][qq] * rn;
    }
    __syncthreads();

    // ---- RBF bank: thread = (q = tid&15, slice sl of 8 x 32 docs) ----
    {
        const int q = tid & 15;
        const int sl = tid >> 4;
        float mu[NK], cc2[NK], acc[NK];
#pragma unroll
        for (int k = 0; k < NK; ++k) {
            mu[k] = mus[k];
            float sg = sigmas[k];
            cc2[k] = -0.5f / (sg * sg);
            acc[k] = 0.f;
        }
        const float* row = sim_t + q * SIMP + sl * 32;
#pragma unroll
        for (int i = 0; i < 8; ++i) {
            float4 s4 = *(const float4*)(row + i * 4);
#pragma unroll
            for (int k = 0; k < NK; ++k) {
                float e0 = s4.x - mu[k], e1 = s4.y - mu[k];
                float e2 = s4.z - mu[k], e3 = s4.w - mu[k];
                acc[k] += __expf(cc2[k]*e0*e0) + __expf(cc2[k]*e1*e1)
                        + __expf(cc2[k]*e2*e2) + __expf(cc2[k]*e3*e3);
            }
        }
#pragma unroll
        for (int k = 0; k < NK; ++k) red_s[(k * NQ + q) * 8 + sl] = acc[k];
    }
    __syncthreads();

    // NK*NQ = 176 > BLOCK = 128: stride the write (R3 bug class).
    for (int t = tid; t < NK * NQ; t += BLOCK) {
        float r = 0.f;
#pragma unroll
        for (int j = 0; j < 8; ++j) r += red_s[t * 8 + j];
        part[blk * (NK * NQ) + t] = r;
    }
}

// ---------------- Kernel 2: sum partials, masked log-sum over q, FC ----------------
__global__ void knrm_final(const float* __restrict__ part,
                           const int*   __restrict__ qtoks,
                           const float* __restrict__ fc_w,
                           const float* __restrict__ fc_b,
                           float*       __restrict__ out) {
    __shared__ float red[NK * NQ];
    __shared__ float ks[NK];
    int b = blockIdx.x;
    int t = threadIdx.x;
    if (t < NK * NQ) {
        int q = t & 15;
        float r = 0.f;
        for (int j = 0; j < BLOCKS_PER_B; ++j)
            r += part[(b * BLOCKS_PER_B + j) * (NK * NQ) + t];
        red[t] = (qtoks[b * NQ + q] != 0) ? logf(r + 1e-6f) : 0.f;
    }
    __syncthreads();
    if (t < NK) {
        float s = 0.f;
        for (int q = 0; q < NQ; ++q) s += red[t * NQ + q];
        ks[t] = s * fc_w[t];
    }
    __syncthreads();
    if (t == 0) {
        float s = fc_b[0];
        for (int k = 0; k < NK; ++k) s += ks[k];
        out[b] = s;
    }
}

extern "C" void kernel_launch(void* const* d_in, const int* in_sizes, int n_in,
                              void* d_out, int out_size, void* d_ws, size_t ws_size,
                              hipStream_t stream) {
    const int*   doctoks   = (const int*)  d_in[0];   // [128,1024]
    const int*   querytoks = (const int*)  d_in[1];   // [128,16]
    // d_in[2] = query_idf: unused by the reference
    const float* emb       = (const float*)d_in[3];   // [100000,300]
    const float* mus       = (const float*)d_in[4];   // [11]
    const float* sigmas    = (const float*)d_in[5];   // [11]
    const float* fc_w      = (const float*)d_in[6];   // [1,11]
    const float* fc_b      = (const float*)d_in[7];   // [1]
    float* out = (float*)d_out;                        // [128]

    float* part = (float*)d_ws;                        // [512][176] floats

    knrm_main<<<NB * BLOCKS_PER_B, BLOCK, 0, stream>>>(doctoks, querytoks, emb,
                                                       mus, sigmas, part);
    knrm_final<<<NB, 192, 0, stream>>>(part, querytoks, fc_w, fc_b, out);
}